// Round 2
// baseline (2195.333 us; speedup 1.0000x reference)
//
#include <hip/hip_runtime.h>
#include <cstdint>
#include <cstddef>

// Sizes (fixed by the problem)
#define QLD 1544          // q row stride (16B-aligned), cols [0,1540) valid
#define NQPAD 1664        // padded N dim for q-GEMM (13 * 128)
#define CHB 2             // batches per chunk
#define CHE (CHB * 64 * 64)   // edges per chunk = 8192

typedef __bf16 bf16x8 __attribute__((ext_vector_type(8)));
typedef float  f32x4  __attribute__((ext_vector_type(4)));
typedef unsigned short ushort_t;

__device__ __forceinline__ unsigned short f2bf(float f) {
  union { float f; unsigned u; } v; v.f = f;
  unsigned r = v.u + 0x7fffu + ((v.u >> 16) & 1u);
  return (unsigned short)(r >> 16);
}
__device__ __forceinline__ float bf2f(unsigned short h) {
  union { unsigned u; float f; } v; v.u = ((unsigned)h) << 16;
  return v.f;
}
__device__ __forceinline__ float elu_f(float x) { return x > 0.f ? x : expm1f(x); }

// ---------------- zero helper ----------------
__global__ void k_zero(float* p, int n) {
  int i = blockIdx.x * blockDim.x + threadIdx.x;
  if (i < n) p[i] = 0.f;
}

// ---------------- GIN aggregation: h0[b,i,c*128+f] = sum_j A[b,c,i,j] x[b,j,f] ----------------
// also copies x into concat[:, 0:128]
__global__ void k_agg(const float* __restrict__ x, const float* __restrict__ adjs,
                      const float* __restrict__ flags,
                      float* __restrict__ h0, float* __restrict__ concat) {
  const int bi = blockIdx.x;           // 0..1023  (b*64+i)
  const int b = bi >> 6, i = bi & 63;
  const int f = threadIdx.x;           // 0..127
  __shared__ float sa[64], sm[64];
  if (f < 64) {
    float m = flags[b * 64 + i] * flags[b * 64 + f];
    float a = adjs[(size_t)(b * 64 + i) * 64 + f] * m;
    sa[f] = a; sm[f] = m;
  }
  __syncthreads();
  float s0 = 0.f, s1 = 0.f;
  const float* xb = x + (size_t)b * 64 * 128;
  for (int j = 0; j < 64; ++j) {
    float xv = xb[j * 128 + f];
    s0 = fmaf(sa[j], xv, s0);
    s1 = fmaf(sm[j] - sa[j], xv, s1);
  }
  h0[(size_t)bi * 256 + f]       = s0;
  h0[(size_t)bi * 256 + 128 + f] = s1;
  concat[(size_t)bi * 384 + f]   = xb[i * 128 + f];
}

// ---------------- small fp32 GEMM: C = act(A@B + bias) * rowscale ----------------
__global__ __launch_bounds__(256) void k_sgemm(
    const float* __restrict__ A, const float* __restrict__ Bm,
    float* __restrict__ Cf, ushort_t* __restrict__ Cb,
    const float* __restrict__ bias, const float* __restrict__ rowscale,
    int K, int lda, int ldb, int ldc, int act) {
  __shared__ float As[64 * 17];   // padded stride 17 to break bank conflicts
  __shared__ float Bs[16 * 64];
  const int tid = threadIdx.x;
  const int tx = tid & 15, ty = tid >> 4;
  const int m0 = blockIdx.y * 64, n0 = blockIdx.x * 64;
  float acc[4][4] = {};
  for (int k0 = 0; k0 < K; k0 += 16) {
#pragma unroll
    for (int i = 0; i < 4; i++) {
      int e = tid + i * 256;
      int r = e >> 4, c = e & 15;
      As[r * 17 + c] = A[(size_t)(m0 + r) * lda + k0 + c];
      int rb = e >> 6, cb = e & 63;
      Bs[e] = Bm[(size_t)(k0 + rb) * ldb + n0 + cb];
    }
    __syncthreads();
#pragma unroll
    for (int kk = 0; kk < 16; kk++) {
      float av[4], bv[4];
#pragma unroll
      for (int i = 0; i < 4; i++) av[i] = As[(ty * 4 + i) * 17 + kk];
#pragma unroll
      for (int j = 0; j < 4; j++) bv[j] = Bs[kk * 64 + tx * 4 + j];
#pragma unroll
      for (int i = 0; i < 4; i++)
#pragma unroll
        for (int j = 0; j < 4; j++) acc[i][j] = fmaf(av[i], bv[j], acc[i][j]);
    }
    __syncthreads();
  }
#pragma unroll
  for (int i = 0; i < 4; i++) {
    const int mm = m0 + ty * 4 + i;
    const float rs = rowscale ? rowscale[mm] : 1.f;
#pragma unroll
    for (int j = 0; j < 4; j++) {
      const int nn = n0 + tx * 4 + j;
      float v = acc[i][j] + (bias ? bias[nn] : 0.f);
      if (act == 1) v = elu_f(v);
      else if (act == 2) v = tanhf(v);
      v *= rs;
      if (Cf) Cf[(size_t)mm * ldc + nn] = v;
      if (Cb) Cb[(size_t)mm * ldc + nn] = f2bf(v);
    }
  }
}

// ---------------- transpose + cast fp32 -> bf16 ----------------
__global__ void k_castT(const float* __restrict__ in, ushort_t* __restrict__ out,
                        int R, int C, int Cpad, int r0, int ld) {
  __shared__ float t[32][33];
  const int rb = blockIdx.y * 32, cb = blockIdx.x * 32;
  const int tx = threadIdx.x, ty = threadIdx.y;
#pragma unroll
  for (int dy = 0; dy < 32; dy += 8) {
    int r = rb + ty + dy, c = cb + tx;
    t[ty + dy][tx] = (r < R && c < C) ? in[(size_t)(r0 + r) * ld + c] : 0.f;
  }
  __syncthreads();
#pragma unroll
  for (int dy = 0; dy < 32; dy += 8) {
    int c = cb + ty + dy, r = rb + tx;
    if (c < Cpad && r < R) out[(size_t)c * R + r] = f2bf(t[tx][ty + dy]);
  }
}

// ---------------- plain cast fp32 -> bf16 ----------------
__global__ void k_cast(const float* __restrict__ in, ushort_t* __restrict__ out, int n) {
  int i = blockIdx.x * blockDim.x + threadIdx.x;
  if (i < n) out[i] = f2bf(in[i]);
}

// ---------------- bf16 MFMA GEMM (128x128 tile, BK=32, 4 waves, 4x4 frags) ----------------
__global__ __launch_bounds__(256) void k_gemm(
    const ushort_t* __restrict__ A, const ushort_t* __restrict__ BT,
    float* __restrict__ outF, ushort_t* __restrict__ outB,
    int K, int lda, int ldb, int ldc, int ncap) {
  __shared__ __align__(16) ushort_t As[128 * 32];
  __shared__ __align__(16) ushort_t Bs[128 * 32];
  const int tid = threadIdx.x;
  const int lane = tid & 63;
  const int wv = tid >> 6;
  const int m0 = blockIdx.y * 128;
  const int n0 = blockIdx.x * 128;
  const int wm = wv >> 1, wn = wv & 1;

  f32x4 z4 = {0.f, 0.f, 0.f, 0.f};
  f32x4 acc[4][4];
#pragma unroll
  for (int i = 0; i < 4; i++)
#pragma unroll
    for (int j = 0; j < 4; j++) acc[i][j] = z4;

  const int r1 = tid >> 2;           // 0..63
  const int c1 = (tid & 3) * 8;      // element offset (16B units)
  const ushort_t* Ag0 = A + (size_t)(m0 + r1) * lda + c1;
  const ushort_t* Ag1 = Ag0 + (size_t)64 * lda;
  const ushort_t* Bg0 = BT + (size_t)(n0 + r1) * ldb + c1;
  const ushort_t* Bg1 = Bg0 + (size_t)64 * ldb;
  ushort_t* As0 = &As[r1 * 32 + c1];
  ushort_t* As1 = &As[(r1 + 64) * 32 + c1];
  ushort_t* Bs0 = &Bs[r1 * 32 + c1];
  ushort_t* Bs1 = &Bs[(r1 + 64) * 32 + c1];

  const int fr = lane & 15;          // m/n within frag
  const int fq = (lane >> 4) * 8;    // k offset

  for (int k0 = 0; k0 < K; k0 += 32) {
    *(uint4*)As0 = *(const uint4*)(Ag0 + k0);
    *(uint4*)As1 = *(const uint4*)(Ag1 + k0);
    *(uint4*)Bs0 = *(const uint4*)(Bg0 + k0);
    *(uint4*)Bs1 = *(const uint4*)(Bg1 + k0);
    __syncthreads();
    bf16x8 af[4], bfv[4];
#pragma unroll
    for (int f = 0; f < 4; ++f) {
      af[f]  = *reinterpret_cast<const bf16x8*>(&As[(wm * 64 + f * 16 + fr) * 32 + fq]);
      bfv[f] = *reinterpret_cast<const bf16x8*>(&Bs[(wn * 64 + f * 16 + fr) * 32 + fq]);
    }
#pragma unroll
    for (int fm = 0; fm < 4; ++fm)
#pragma unroll
      for (int fn = 0; fn < 4; ++fn)
        acc[fm][fn] = __builtin_amdgcn_mfma_f32_16x16x32_bf16(af[fm], bfv[fn], acc[fm][fn], 0, 0, 0);
    __syncthreads();
  }

  // C/D layout: col = lane&15, row = (lane>>4)*4 + reg  [m89-verified]
  const int er = (lane >> 4) * 4;
  const int ec = lane & 15;
#pragma unroll
  for (int fm = 0; fm < 4; ++fm) {
#pragma unroll
    for (int fn = 0; fn < 4; ++fn) {
      const int nn = n0 + wn * 64 + fn * 16 + ec;
      if (nn >= ncap) continue;
#pragma unroll
      for (int r = 0; r < 4; ++r) {
        const int mm = m0 + wm * 64 + fm * 16 + er + r;
        float v = acc[fm][fn][r];
        if (outF) outF[(size_t)mm * ldc + nn] = v;
        if (outB) outB[(size_t)mm * ldc + nn] = f2bf(v);
      }
    }
  }
}

// ---------------- d[n] = sum_m b2t[m] * W1r[2+m, n] ----------------
__global__ void k_dvec(const float* __restrict__ b2t, const float* __restrict__ W1r,
                       float* __restrict__ dvec) {
  int n = blockIdx.x * 256 + threadIdx.x;
  if (n >= 1540) return;
  float s = 0.f;
  for (int m2 = 0; m2 < 768; ++m2)
    s = fmaf(b2t[m2], W1r[(size_t)(2 + m2) * 1540 + n], s);
  dvec[n] = s;
}

// ---------------- BN stats over the virtual h1 (recomputed, never stored) ----------------
__global__ __launch_bounds__(256) void k_stats(
    const float* __restrict__ UV, const float* __restrict__ adjs,
    const float* __restrict__ flags, const float* __restrict__ W1t,
    const float* __restrict__ b1t, float* __restrict__ colsum, float* __restrict__ colss) {
  const int bi = blockIdx.x, b = bi >> 6, i = bi & 63;
  const int t = threadIdx.x;
  __shared__ float sa0[64], sa1[64];
  if (t < 64) {
    float m = flags[b * 64 + i] * flags[b * 64 + t];
    float a = adjs[(size_t)(b * 64 + i) * 64 + t] * m;
    sa0[t] = a; sa1[t] = m - a;
  }
  __syncthreads();
  const float* Urow = UV + (size_t)bi * 3072;
  float u[6], w0[6], w1[6], bb[6], sum[6], ss[6];
#pragma unroll
  for (int c = 0; c < 6; c++) {
    int n = t + 256 * c;
    u[c] = Urow[n]; w0[c] = W1t[n]; w1[c] = W1t[1536 + n]; bb[c] = b1t[n];
    sum[c] = 0.f; ss[c] = 0.f;
  }
  for (int j = 0; j < 64; j++) {
    const float* Vrow = UV + (size_t)(b * 64 + j) * 3072 + 1536;
    float a0 = sa0[j], a1 = sa1[j];
#pragma unroll
    for (int c = 0; c < 6; c++) {
      float h = u[c] + Vrow[t + 256 * c] + a0 * w0[c] + a1 * w1[c] + bb[c];
      sum[c] += h; ss[c] = fmaf(h, h, ss[c]);
    }
  }
#pragma unroll
  for (int c = 0; c < 6; c++) {
    atomicAdd(&colsum[t + 256 * c], sum[c]);
    atomicAdd(&colss[t + 256 * c], ss[c]);
  }
}

// ---------------- finalize BN scale/shift ----------------
__global__ void k_bnfin(const float* __restrict__ colsum, const float* __restrict__ colss,
                        const float* __restrict__ gamma, const float* __restrict__ beta,
                        float* __restrict__ bns, float* __restrict__ bnt) {
  int n = blockIdx.x * 256 + threadIdx.x;
  if (n >= 1536) return;
  float mu = colsum[n] * (1.f / 65536.f);
  float var = colss[n] * (1.f / 65536.f) - mu * mu;
  float s = gamma[n] * rsqrtf(var + 1e-5f);
  bns[n] = s;
  bnt[n] = beta[n] - mu * s;
}

// ---------------- hmid chunk = bf16(elu(h1*s + t)), bi in [bi0, bi0+128) ----------------
__global__ __launch_bounds__(256) void k_act(
    const float* __restrict__ UV, const float* __restrict__ adjs,
    const float* __restrict__ flags, const float* __restrict__ W1t,
    const float* __restrict__ b1t, const float* __restrict__ bns,
    const float* __restrict__ bnt, ushort_t* __restrict__ hmid, int bi0) {
  const int bil = blockIdx.x;                 // local row-chunk index
  const int bi = bi0 + bil, b = bi >> 6, i = bi & 63;
  const int t = threadIdx.x;
  __shared__ float sa0[64], sa1[64];
  if (t < 64) {
    float m = flags[b * 64 + i] * flags[b * 64 + t];
    float a = adjs[(size_t)(b * 64 + i) * 64 + t] * m;
    sa0[t] = a; sa1[t] = m - a;
  }
  __syncthreads();
  const float* Urow = UV + (size_t)bi * 3072;
  float u[6], w0[6], w1[6], bb[6], s6[6], t6[6];
#pragma unroll
  for (int c = 0; c < 6; c++) {
    int n = t + 256 * c;
    u[c] = Urow[n]; w0[c] = W1t[n]; w1[c] = W1t[1536 + n]; bb[c] = b1t[n];
    s6[c] = bns[n]; t6[c] = bnt[n];
  }
  for (int j = 0; j < 64; j++) {
    const float* Vrow = UV + (size_t)(b * 64 + j) * 3072 + 1536;
    ushort_t* hrow = hmid + ((size_t)bil * 64 + j) * 1536;
    float a0 = sa0[j], a1 = sa1[j];
#pragma unroll
    for (int c = 0; c < 6; c++) {
      int n = t + 256 * c;
      float h = u[c] + Vrow[n] + a0 * w0[c] + a1 * w1[c] + bb[c];
      float v = fmaf(h, s6[c], t6[c]);
      hrow[n] = f2bf(elu_f(v));
    }
  }
}

// ---------------- score chunk: block per unordered pair (i<=j), b = b0 + blockIdx.z ----------------
__global__ __launch_bounds__(256) void k_score(
    const ushort_t* __restrict__ q, const float* __restrict__ adjs,
    const float* __restrict__ flags, const float* __restrict__ dvec,
    const float* __restrict__ W1r, const float* __restrict__ b1r,
    const float* __restrict__ W2r, const float* __restrict__ b2r,
    float* __restrict__ out, int b0) {
  const int i = blockIdx.x, j = blockIdx.y, bl = blockIdx.z;
  const int b = b0 + bl;
  if (i > j) return;
  const int t = threadIdx.x;
  if (i == j) { if (t == 0) out[((size_t)b * 64 + i) * 64 + j] = 0.f; return; }
  float fi = flags[b * 64 + i], fj = flags[b * 64 + j], m = fi * fj;
  float adij = adjs[((size_t)b * 64 + i) * 64 + j];
  float adji = adjs[((size_t)b * 64 + j) * 64 + i];
  float a0ij = adij * m, a1ij = m - a0ij;
  float a0ji = adji * m, a1ji = m - a0ji;
  const ushort_t* qij = q + (((size_t)bl * 64 + i) * 64 + j) * QLD;
  const ushort_t* qji = q + (((size_t)bl * 64 + j) * 64 + i) * QLD;
  float sij = 0.f, sji = 0.f;
  for (int n = t; n < 1540; n += 256) {
    float quv = bf2f(qij[n]) + bf2f(qji[n]) + 2.f * dvec[n];
    float base = m * quv + b1r[n];
    float w0 = W1r[n], w1 = W1r[1540 + n], w2 = W2r[n];
    float zij = base + a0ij * w0 + a1ij * w1;
    float zji = base + a0ji * w0 + a1ji * w1;
    sij = fmaf(elu_f(zij), w2, sij);
    sji = fmaf(elu_f(zji), w2, sji);
  }
  __shared__ float red[512];
  red[t] = sij; red[256 + t] = sji;
  __syncthreads();
  for (int s2 = 128; s2 > 0; s2 >>= 1) {
    if (t < s2) { red[t] += red[t + s2]; red[256 + t] += red[256 + t + s2]; }
    __syncthreads();
  }
  if (t == 0) {
    out[((size_t)b * 64 + i) * 64 + j] = red[0]   + b2r[0];
    out[((size_t)b * 64 + j) * 64 + i] = red[256] + b2r[0];
  }
}

extern "C" void kernel_launch(void* const* d_in, const int* in_sizes, int n_in,
                              void* d_out, int out_size, void* d_ws, size_t ws_size,
                              hipStream_t stream) {
  const float* x     = (const float*)d_in[0];
  const float* adjs  = (const float*)d_in[1];
  const float* flags = (const float*)d_in[2];
  const float* Wg    = (const float*)d_in[3];
  const float* bg    = (const float*)d_in[4];
  const float* Wout  = (const float*)d_in[5];
  const float* bout  = (const float*)d_in[6];
  const float* W1t   = (const float*)d_in[7];
  const float* b1t   = (const float*)d_in[8];
  const float* gamma = (const float*)d_in[9];
  const float* beta  = (const float*)d_in[10];
  const float* W2t   = (const float*)d_in[11];
  const float* b2t   = (const float*)d_in[12];
  const float* W1r   = (const float*)d_in[13];
  const float* b1r   = (const float*)d_in[14];
  const float* W2r   = (const float*)d_in[15];
  const float* b2r   = (const float*)d_in[16];
  float* out_score = (float*)d_out;
  float* out_xo    = (float*)d_out + 65536;

  uint8_t* ws = (uint8_t*)d_ws;
  size_t off = 0;
  auto alloc = [&](size_t bytes) -> void* {
    void* p = ws + off;
    off += (bytes + 255) & ~(size_t)255;
    return p;
  };
  float*    h0      = (float*)   alloc((size_t)1024 * 256 * 4);
  float*    concat  = (float*)   alloc((size_t)1024 * 384 * 4);
  ushort_t* xo_bf   = (ushort_t*)alloc((size_t)1024 * 768 * 2);
  ushort_t* W1tT    = (ushort_t*)alloc((size_t)3072 * 768 * 2);
  ushort_t* W2t_bf  = (ushort_t*)alloc((size_t)1536 * 768 * 2);
  ushort_t* WrxT    = (ushort_t*)alloc((size_t)NQPAD * 768 * 2);
  ushort_t* WcT     = (ushort_t*)alloc((size_t)NQPAD * 1536 * 2);
  float*    UV      = (float*)   alloc((size_t)1024 * 3072 * 4);
  float*    dvec    = (float*)   alloc((size_t)1664 * 4);
  float*    colsum  = (float*)   alloc((size_t)1536 * 4);
  float*    colss   = (float*)   alloc((size_t)1536 * 4);
  float*    bns     = (float*)   alloc((size_t)1536 * 4);
  float*    bnt     = (float*)   alloc((size_t)1536 * 4);
  ushort_t* hmid_c  = (ushort_t*)alloc((size_t)CHE * 1536 * 2);   // 24 MB chunk
  ushort_t* q_c     = (ushort_t*)alloc((size_t)CHE * QLD * 2);    // 24 MB chunk
  (void)ws_size; (void)in_sizes; (void)n_in; (void)out_size;

  // BN accumulators must be zeroed every launch (ws is poisoned)
  k_zero<<<dim3(12), dim3(256), 0, stream>>>(colsum, 3072);

  // GIN chain (fp32 — x_o is a direct output)
  k_agg<<<dim3(1024), dim3(128), 0, stream>>>(x, adjs, flags, h0, concat);
  k_sgemm<<<dim3(4, 16), dim3(256), 0, stream>>>(h0, Wg, concat + 128, (ushort_t*)nullptr,
                                                 bg, flags, 256, 256, 256, 384, 1);
  k_sgemm<<<dim3(12, 16), dim3(256), 0, stream>>>(concat, Wout, out_xo, xo_bf,
                                                  bout, flags, 384, 384, 768, 768, 2);

  // weight casts / transposes
  k_castT<<<dim3(48, 24), dim3(32, 8), 0, stream>>>(W1t, W1tT, 768, 1536, 1536, 2, 1536);
  k_castT<<<dim3(48, 24), dim3(32, 8), 0, stream>>>(W1t, W1tT + (size_t)1536 * 768, 768, 1536, 1536, 770, 1536);
  k_castT<<<dim3(52, 24), dim3(32, 8), 0, stream>>>(W1r, WrxT, 768, 1540, NQPAD, 2, 1540);
  k_cast<<<dim3(4608), dim3(256), 0, stream>>>(W2t, W2t_bf, 1536 * 768);

  // UV = x_o @ [W1t_i | W1t_j]   (fp32 out)
  k_gemm<<<dim3(24, 8), dim3(256), 0, stream>>>(xo_bf, W1tT, UV, (ushort_t*)nullptr,
                                                768, 768, 768, 3072, 3072);
  // WcT = (W2t @ W1r[2:770])^T  (bf16 out, padded rows zero via WrxT zero-pad)
  k_gemm<<<dim3(12, 13), dim3(256), 0, stream>>>(WrxT, W2t_bf, (float*)nullptr, WcT,
                                                 768, 768, 768, 1536, 1536);
  k_dvec<<<dim3(7), dim3(256), 0, stream>>>(b2t, W1r, dvec);

  // BN stats over virtual h1 (full dataset), finalize
  k_stats<<<dim3(1024), dim3(256), 0, stream>>>(UV, adjs, flags, W1t, b1t, colsum, colss);
  k_bnfin<<<dim3(6), dim3(256), 0, stream>>>(colsum, colss, gamma, beta, bns, bnt);

  // chunked heavy pipeline: act -> q-GEMM -> score, CHB batches at a time
  for (int b0 = 0; b0 < 16; b0 += CHB) {
    k_act<<<dim3(CHB * 64), dim3(256), 0, stream>>>(UV, adjs, flags, W1t, b1t, bns, bnt,
                                                    hmid_c, b0 * 64);
    k_gemm<<<dim3(13, CHE / 128), dim3(256), 0, stream>>>(hmid_c, WcT, (float*)nullptr, q_c,
                                                          1536, 1536, 1536, QLD, 1540);
    k_score<<<dim3(64, 64, CHB), dim3(256), 0, stream>>>(q_c, adjs, flags, dvec,
                                                         W1r, b1r, W2r, b2r, out_score, b0);
  }
}

// Round 3
// 1135.424 us; speedup vs baseline: 1.9335x; 1.9335x over previous
//
#include <hip/hip_runtime.h>
#include <cstdint>
#include <cstddef>

// Sizes (fixed by the problem)
#define QLD 1544          // q row stride (16B-aligned), cols [0,1540) valid
#define NQPAD 1664        // padded N dim for q-GEMM (13 * 128)

typedef __bf16 bf16x8 __attribute__((ext_vector_type(8)));
typedef float  f32x4  __attribute__((ext_vector_type(4)));
typedef unsigned short ushort_t;

__device__ __forceinline__ unsigned short f2bf(float f) {
  union { float f; unsigned u; } v; v.f = f;
  unsigned r = v.u + 0x7fffu + ((v.u >> 16) & 1u);
  return (unsigned short)(r >> 16);
}
__device__ __forceinline__ float bf2f(unsigned short h) {
  union { unsigned u; float f; } v; v.u = ((unsigned)h) << 16;
  return v.f;
}
__device__ __forceinline__ float elu_f(float x) { return x > 0.f ? x : expm1f(x); }

// ---------------- zero helper ----------------
__global__ void k_zero(float* p, int n) {
  int i = blockIdx.x * blockDim.x + threadIdx.x;
  if (i < n) p[i] = 0.f;
}

// ---------------- GIN aggregation: h0[b,i,c*128+f] = sum_j A[b,c,i,j] x[b,j,f] ----------------
__global__ void k_agg(const float* __restrict__ x, const float* __restrict__ adjs,
                      const float* __restrict__ flags,
                      float* __restrict__ h0, float* __restrict__ concat) {
  const int bi = blockIdx.x;           // 0..1023  (b*64+i)
  const int b = bi >> 6, i = bi & 63;
  const int f = threadIdx.x;           // 0..127
  __shared__ float sa[64], sm[64];
  if (f < 64) {
    float m = flags[b * 64 + i] * flags[b * 64 + f];
    float a = adjs[(size_t)(b * 64 + i) * 64 + f] * m;
    sa[f] = a; sm[f] = m;
  }
  __syncthreads();
  float s0 = 0.f, s1 = 0.f;
  const float* xb = x + (size_t)b * 64 * 128;
  for (int j = 0; j < 64; ++j) {
    float xv = xb[j * 128 + f];
    s0 = fmaf(sa[j], xv, s0);
    s1 = fmaf(sm[j] - sa[j], xv, s1);
  }
  h0[(size_t)bi * 256 + f]       = s0;
  h0[(size_t)bi * 256 + 128 + f] = s1;
  concat[(size_t)bi * 384 + f]   = xb[i * 128 + f];
}

// ---------------- small fp32 GEMM: C = act(A@B + bias) * rowscale ----------------
__global__ __launch_bounds__(256) void k_sgemm(
    const float* __restrict__ A, const float* __restrict__ Bm,
    float* __restrict__ Cf, ushort_t* __restrict__ Cb,
    const float* __restrict__ bias, const float* __restrict__ rowscale,
    int K, int lda, int ldb, int ldc, int act) {
  __shared__ float As[64 * 17];
  __shared__ float Bs[16 * 64];
  const int tid = threadIdx.x;
  const int tx = tid & 15, ty = tid >> 4;
  const int m0 = blockIdx.y * 64, n0 = blockIdx.x * 64;
  float acc[4][4] = {};
  for (int k0 = 0; k0 < K; k0 += 16) {
#pragma unroll
    for (int i = 0; i < 4; i++) {
      int e = tid + i * 256;
      int r = e >> 4, c = e & 15;
      As[r * 17 + c] = A[(size_t)(m0 + r) * lda + k0 + c];
      int rb = e >> 6, cb = e & 63;
      Bs[e] = Bm[(size_t)(k0 + rb) * ldb + n0 + cb];
    }
    __syncthreads();
#pragma unroll
    for (int kk = 0; kk < 16; kk++) {
      float av[4], bv[4];
#pragma unroll
      for (int i = 0; i < 4; i++) av[i] = As[(ty * 4 + i) * 17 + kk];
#pragma unroll
      for (int j = 0; j < 4; j++) bv[j] = Bs[kk * 64 + tx * 4 + j];
#pragma unroll
      for (int i = 0; i < 4; i++)
#pragma unroll
        for (int j = 0; j < 4; j++) acc[i][j] = fmaf(av[i], bv[j], acc[i][j]);
    }
    __syncthreads();
  }
#pragma unroll
  for (int i = 0; i < 4; i++) {
    const int mm = m0 + ty * 4 + i;
    const float rs = rowscale ? rowscale[mm] : 1.f;
#pragma unroll
    for (int j = 0; j < 4; j++) {
      const int nn = n0 + tx * 4 + j;
      float v = acc[i][j] + (bias ? bias[nn] : 0.f);
      if (act == 1) v = elu_f(v);
      else if (act == 2) v = tanhf(v);
      v *= rs;
      if (Cf) Cf[(size_t)mm * ldc + nn] = v;
      if (Cb) Cb[(size_t)mm * ldc + nn] = f2bf(v);
    }
  }
}

// ---------------- transpose + cast fp32 -> bf16 ----------------
__global__ void k_castT(const float* __restrict__ in, ushort_t* __restrict__ out,
                        int R, int C, int Cpad, int r0, int ld) {
  __shared__ float t[32][33];
  const int rb = blockIdx.y * 32, cb = blockIdx.x * 32;
  const int tx = threadIdx.x, ty = threadIdx.y;
#pragma unroll
  for (int dy = 0; dy < 32; dy += 8) {
    int r = rb + ty + dy, c = cb + tx;
    t[ty + dy][tx] = (r < R && c < C) ? in[(size_t)(r0 + r) * ld + c] : 0.f;
  }
  __syncthreads();
#pragma unroll
  for (int dy = 0; dy < 32; dy += 8) {
    int c = cb + ty + dy, r = rb + tx;
    if (c < Cpad && r < R) out[(size_t)c * R + r] = f2bf(t[tx][ty + dy]);
  }
}

// ---------------- plain cast fp32 -> bf16 ----------------
__global__ void k_cast(const float* __restrict__ in, ushort_t* __restrict__ out, int n) {
  int i = blockIdx.x * blockDim.x + threadIdx.x;
  if (i < n) out[i] = f2bf(in[i]);
}

// ---------------- bf16 MFMA GEMM (128x128 tile, BK=32, 4 waves, 4x4 frags) ----------------
__global__ __launch_bounds__(256) void k_gemm(
    const ushort_t* __restrict__ A, const ushort_t* __restrict__ BT,
    float* __restrict__ outF, ushort_t* __restrict__ outB,
    int K, int lda, int ldb, int ldc, int ncap) {
  __shared__ __align__(16) ushort_t As[128 * 32];
  __shared__ __align__(16) ushort_t Bs[128 * 32];
  const int tid = threadIdx.x;
  const int lane = tid & 63;
  const int wv = tid >> 6;
  const int m0 = blockIdx.y * 128;
  const int n0 = blockIdx.x * 128;
  const int wm = wv >> 1, wn = wv & 1;

  f32x4 z4 = {0.f, 0.f, 0.f, 0.f};
  f32x4 acc[4][4];
#pragma unroll
  for (int i = 0; i < 4; i++)
#pragma unroll
    for (int j = 0; j < 4; j++) acc[i][j] = z4;

  const int r1 = tid >> 2;           // 0..63
  const int c1 = (tid & 3) * 8;      // element offset (16B units)
  const ushort_t* Ag0 = A + (size_t)(m0 + r1) * lda + c1;
  const ushort_t* Ag1 = Ag0 + (size_t)64 * lda;
  const ushort_t* Bg0 = BT + (size_t)(n0 + r1) * ldb + c1;
  const ushort_t* Bg1 = Bg0 + (size_t)64 * ldb;
  ushort_t* As0 = &As[r1 * 32 + c1];
  ushort_t* As1 = &As[(r1 + 64) * 32 + c1];
  ushort_t* Bs0 = &Bs[r1 * 32 + c1];
  ushort_t* Bs1 = &Bs[(r1 + 64) * 32 + c1];

  const int fr = lane & 15;          // m/n within frag
  const int fq = (lane >> 4) * 8;    // k offset

  for (int k0 = 0; k0 < K; k0 += 32) {
    *(uint4*)As0 = *(const uint4*)(Ag0 + k0);
    *(uint4*)As1 = *(const uint4*)(Ag1 + k0);
    *(uint4*)Bs0 = *(const uint4*)(Bg0 + k0);
    *(uint4*)Bs1 = *(const uint4*)(Bg1 + k0);
    __syncthreads();
    bf16x8 af[4], bfv[4];
#pragma unroll
    for (int f = 0; f < 4; ++f) {
      af[f]  = *reinterpret_cast<const bf16x8*>(&As[(wm * 64 + f * 16 + fr) * 32 + fq]);
      bfv[f] = *reinterpret_cast<const bf16x8*>(&Bs[(wn * 64 + f * 16 + fr) * 32 + fq]);
    }
#pragma unroll
    for (int fm = 0; fm < 4; ++fm)
#pragma unroll
      for (int fn = 0; fn < 4; ++fn)
        acc[fm][fn] = __builtin_amdgcn_mfma_f32_16x16x32_bf16(af[fm], bfv[fn], acc[fm][fn], 0, 0, 0);
    __syncthreads();
  }

  const int er = (lane >> 4) * 4;
  const int ec = lane & 15;
#pragma unroll
  for (int fm = 0; fm < 4; ++fm) {
#pragma unroll
    for (int fn = 0; fn < 4; ++fn) {
      const int nn = n0 + wn * 64 + fn * 16 + ec;
      if (nn >= ncap) continue;
#pragma unroll
      for (int r = 0; r < 4; ++r) {
        const int mm = m0 + wm * 64 + fm * 16 + er + r;
        float v = acc[fm][fn][r];
        if (outF) outF[(size_t)mm * ldc + nn] = v;
        if (outB) outB[(size_t)mm * ldc + nn] = f2bf(v);
      }
    }
  }
}

// ---------------- d[n] = sum_m b2t[m] * W1r[2+m, n] ----------------
__global__ void k_dvec(const float* __restrict__ b2t, const float* __restrict__ W1r,
                       float* __restrict__ dvec) {
  int n = blockIdx.x * 256 + threadIdx.x;
  if (n >= 1540) return;
  float s = 0.f;
  for (int m2 = 0; m2 < 768; ++m2)
    s = fmaf(b2t[m2], W1r[(size_t)(2 + m2) * 1540 + n], s);
  dvec[n] = s;
}

// ---------------- BN stats over virtual h1 (j-split for occupancy) ----------------
// grid (1024, 4): block handles rows (bi, j0..j0+15)
__global__ __launch_bounds__(256) void k_stats(
    const float* __restrict__ UV, const float* __restrict__ adjs,
    const float* __restrict__ flags, const float* __restrict__ W1t,
    const float* __restrict__ b1t, float* __restrict__ colsum, float* __restrict__ colss) {
  const int bi = blockIdx.x, b = bi >> 6;
  const int j0 = blockIdx.y * 16;
  const int t = threadIdx.x;
  const float fi = flags[bi];
  const float* Urow = UV + (size_t)bi * 3072;
  float u[6], w0[6], w1[6], bb[6], sum[6], ss[6];
#pragma unroll
  for (int c = 0; c < 6; c++) {
    int n = t + 256 * c;
    u[c] = Urow[n]; w0[c] = W1t[n]; w1[c] = W1t[1536 + n]; bb[c] = b1t[n];
    sum[c] = 0.f; ss[c] = 0.f;
  }
  for (int j = j0; j < j0 + 16; ++j) {
    float m = fi * flags[b * 64 + j];
    float a0 = adjs[(size_t)bi * 64 + j] * m;
    float a1 = m - a0;
    const float* Vrow = UV + (size_t)(b * 64 + j) * 3072 + 1536;
#pragma unroll
    for (int c = 0; c < 6; c++) {
      float h = u[c] + Vrow[t + 256 * c] + a0 * w0[c] + a1 * w1[c] + bb[c];
      sum[c] += h; ss[c] = fmaf(h, h, ss[c]);
    }
  }
#pragma unroll
  for (int c = 0; c < 6; c++) {
    atomicAdd(&colsum[t + 256 * c], sum[c]);
    atomicAdd(&colss[t + 256 * c], ss[c]);
  }
}

// ---------------- finalize BN scale/shift ----------------
__global__ void k_bnfin(const float* __restrict__ colsum, const float* __restrict__ colss,
                        const float* __restrict__ gamma, const float* __restrict__ beta,
                        float* __restrict__ bns, float* __restrict__ bnt) {
  int n = blockIdx.x * 256 + threadIdx.x;
  if (n >= 1536) return;
  float mu = colsum[n] * (1.f / 65536.f);
  float var = colss[n] * (1.f / 65536.f) - mu * mu;
  float s = gamma[n] * rsqrtf(var + 1e-5f);
  bns[n] = s;
  bnt[n] = beta[n] - mu * s;
}

// ---------------- hmid: edge-parallel, one block per edge row ----------------
__global__ __launch_bounds__(256) void k_act2(
    const float* __restrict__ UV, const float* __restrict__ adjs,
    const float* __restrict__ flags, const float* __restrict__ W1t,
    const float* __restrict__ b1t, const float* __restrict__ bns,
    const float* __restrict__ bnt, ushort_t* __restrict__ hmid, int bi0) {
  const int e = blockIdx.x;            // local edge index within chunk
  const int bi = bi0 + (e >> 6);       // global b*64+i
  const int j = e & 63;
  const int b = bi >> 6;
  const int t = threadIdx.x;
  const float m = flags[bi] * flags[b * 64 + j];
  const float a0 = adjs[(size_t)bi * 64 + j] * m;
  const float a1 = m - a0;
  const float* Urow = UV + (size_t)bi * 3072;
  const float* Vrow = UV + (size_t)(b * 64 + j) * 3072 + 1536;
  ushort_t* hrow = hmid + (size_t)e * 1536;
#pragma unroll
  for (int c = 0; c < 6; c++) {
    int n = t + 256 * c;
    float h = Urow[n] + Vrow[n] + a0 * W1t[n] + a1 * W1t[1536 + n] + b1t[n];
    float v = fmaf(h, bns[n], bnt[n]);
    hrow[n] = f2bf(elu_f(v));
  }
}

// ---------------- score chunk: block per unordered pair (i<=j), b = b0 + blockIdx.z ----------------
__global__ __launch_bounds__(256) void k_score(
    const ushort_t* __restrict__ q, const float* __restrict__ adjs,
    const float* __restrict__ flags, const float* __restrict__ dvec,
    const float* __restrict__ W1r, const float* __restrict__ b1r,
    const float* __restrict__ W2r, const float* __restrict__ b2r,
    float* __restrict__ out, int b0) {
  const int i = blockIdx.x, j = blockIdx.y, bl = blockIdx.z;
  const int b = b0 + bl;
  if (i > j) return;
  const int t = threadIdx.x;
  if (i == j) { if (t == 0) out[((size_t)b * 64 + i) * 64 + j] = 0.f; return; }
  float fi = flags[b * 64 + i], fj = flags[b * 64 + j], m = fi * fj;
  float adij = adjs[((size_t)b * 64 + i) * 64 + j];
  float adji = adjs[((size_t)b * 64 + j) * 64 + i];
  float a0ij = adij * m, a1ij = m - a0ij;
  float a0ji = adji * m, a1ji = m - a0ji;
  const ushort_t* qij = q + (((size_t)bl * 64 + i) * 64 + j) * QLD;
  const ushort_t* qji = q + (((size_t)bl * 64 + j) * 64 + i) * QLD;
  float sij = 0.f, sji = 0.f;
  for (int n = t; n < 1540; n += 256) {
    float quv = bf2f(qij[n]) + bf2f(qji[n]) + 2.f * dvec[n];
    float base = m * quv + b1r[n];
    float w0 = W1r[n], w1 = W1r[1540 + n], w2 = W2r[n];
    float zij = base + a0ij * w0 + a1ij * w1;
    float zji = base + a0ji * w0 + a1ji * w1;
    sij = fmaf(elu_f(zij), w2, sij);
    sji = fmaf(elu_f(zji), w2, sji);
  }
  __shared__ float red[512];
  red[t] = sij; red[256 + t] = sji;
  __syncthreads();
  for (int s2 = 128; s2 > 0; s2 >>= 1) {
    if (t < s2) { red[t] += red[t + s2]; red[256 + t] += red[256 + t + s2]; }
    __syncthreads();
  }
  if (t == 0) {
    out[((size_t)b * 64 + i) * 64 + j] = red[0]   + b2r[0];
    out[((size_t)b * 64 + j) * 64 + i] = red[256] + b2r[0];
  }
}

extern "C" void kernel_launch(void* const* d_in, const int* in_sizes, int n_in,
                              void* d_out, int out_size, void* d_ws, size_t ws_size,
                              hipStream_t stream) {
  const float* x     = (const float*)d_in[0];
  const float* adjs  = (const float*)d_in[1];
  const float* flags = (const float*)d_in[2];
  const float* Wg    = (const float*)d_in[3];
  const float* bg    = (const float*)d_in[4];
  const float* Wout  = (const float*)d_in[5];
  const float* bout  = (const float*)d_in[6];
  const float* W1t   = (const float*)d_in[7];
  const float* b1t   = (const float*)d_in[8];
  const float* gamma = (const float*)d_in[9];
  const float* beta  = (const float*)d_in[10];
  const float* W2t   = (const float*)d_in[11];
  const float* b2t   = (const float*)d_in[12];
  const float* W1r   = (const float*)d_in[13];
  const float* b1r   = (const float*)d_in[14];
  const float* W2r   = (const float*)d_in[15];
  const float* b2r   = (const float*)d_in[16];
  float* out_score = (float*)d_out;
  float* out_xo    = (float*)d_out + 65536;

  uint8_t* ws = (uint8_t*)d_ws;
  size_t off = 0;
  auto alloc = [&](size_t bytes) -> void* {
    void* p = ws + off;
    off += (bytes + 255) & ~(size_t)255;
    return p;
  };
  float*    h0      = (float*)   alloc((size_t)1024 * 256 * 4);
  float*    concat  = (float*)   alloc((size_t)1024 * 384 * 4);
  ushort_t* xo_bf   = (ushort_t*)alloc((size_t)1024 * 768 * 2);
  ushort_t* W1tT    = (ushort_t*)alloc((size_t)3072 * 768 * 2);
  ushort_t* W2t_bf  = (ushort_t*)alloc((size_t)1536 * 768 * 2);
  ushort_t* WrxT    = (ushort_t*)alloc((size_t)NQPAD * 768 * 2);
  ushort_t* WcT     = (ushort_t*)alloc((size_t)NQPAD * 1536 * 2);
  float*    UV      = (float*)   alloc((size_t)1024 * 3072 * 4);
  float*    dvec    = (float*)   alloc((size_t)1664 * 4);
  float*    colsum  = (float*)   alloc((size_t)1536 * 4);
  float*    colss   = (float*)   alloc((size_t)1536 * 4);
  float*    bns     = (float*)   alloc((size_t)1536 * 4);
  float*    bnt     = (float*)   alloc((size_t)1536 * 4);

  // Adaptive chunk size: pick largest CHB (batches per chunk) that fits ws.
  int cb = 2;
  {
    const int cands[4] = {16, 8, 4, 2};
    for (int ci = 0; ci < 4; ++ci) {
      int c = cands[ci];
      size_t need = off + ((size_t)c * 4096 * 1536 * 2 + 256)
                        + ((size_t)c * 4096 * QLD * 2 + 256);
      if (need <= ws_size) { cb = c; break; }
    }
  }
  ushort_t* hmid_c  = (ushort_t*)alloc((size_t)cb * 4096 * 1536 * 2);
  ushort_t* q_c     = (ushort_t*)alloc((size_t)cb * 4096 * QLD * 2);
  (void)in_sizes; (void)n_in; (void)out_size;

  // BN accumulators must be zeroed every launch (ws is poisoned)
  k_zero<<<dim3(12), dim3(256), 0, stream>>>(colsum, 3072);

  // GIN chain (fp32 — x_o is a direct output)
  k_agg<<<dim3(1024), dim3(128), 0, stream>>>(x, adjs, flags, h0, concat);
  k_sgemm<<<dim3(4, 16), dim3(256), 0, stream>>>(h0, Wg, concat + 128, (ushort_t*)nullptr,
                                                 bg, flags, 256, 256, 256, 384, 1);
  k_sgemm<<<dim3(12, 16), dim3(256), 0, stream>>>(concat, Wout, out_xo, xo_bf,
                                                  bout, flags, 384, 384, 768, 768, 2);

  // weight casts / transposes
  k_castT<<<dim3(48, 24), dim3(32, 8), 0, stream>>>(W1t, W1tT, 768, 1536, 1536, 2, 1536);
  k_castT<<<dim3(48, 24), dim3(32, 8), 0, stream>>>(W1t, W1tT + (size_t)1536 * 768, 768, 1536, 1536, 770, 1536);
  k_castT<<<dim3(52, 24), dim3(32, 8), 0, stream>>>(W1r, WrxT, 768, 1540, NQPAD, 2, 1540);
  k_cast<<<dim3(4608), dim3(256), 0, stream>>>(W2t, W2t_bf, 1536 * 768);

  // UV = x_o @ [W1t_i | W1t_j]   (fp32 out)
  k_gemm<<<dim3(24, 8), dim3(256), 0, stream>>>(xo_bf, W1tT, UV, (ushort_t*)nullptr,
                                                768, 768, 768, 3072, 3072);
  // WcT = (W2t @ W1r[2:770])^T  (bf16 out, padded rows zero via WrxT zero-pad)
  k_gemm<<<dim3(12, 13), dim3(256), 0, stream>>>(WrxT, W2t_bf, (float*)nullptr, WcT,
                                                 768, 768, 768, 1536, 1536);
  k_dvec<<<dim3(7), dim3(256), 0, stream>>>(b2t, W1r, dvec);

  // BN stats over virtual h1 (full dataset), finalize
  k_stats<<<dim3(1024, 4), dim3(256), 0, stream>>>(UV, adjs, flags, W1t, b1t, colsum, colss);
  k_bnfin<<<dim3(6), dim3(256), 0, stream>>>(colsum, colss, gamma, beta, bns, bnt);

  // chunked heavy pipeline: act -> q-GEMM -> score, cb batches at a time
  for (int b0 = 0; b0 < 16; b0 += cb) {
    k_act2<<<dim3(cb * 4096), dim3(256), 0, stream>>>(UV, adjs, flags, W1t, b1t, bns, bnt,
                                                      hmid_c, b0 * 64);
    k_gemm<<<dim3(13, cb * 32), dim3(256), 0, stream>>>(hmid_c, WcT, (float*)nullptr, q_c,
                                                        1536, 1536, 1536, QLD, 1540);
    k_score<<<dim3(64, 64, cb), dim3(256), 0, stream>>>(q_c, adjs, flags, dvec,
                                                        W1r, b1r, W2r, b2r, out_score, b0);
  }
}

// Round 4
// 1040.588 us; speedup vs baseline: 2.1097x; 1.0911x over previous
//
#include <hip/hip_runtime.h>
#include <cstdint>
#include <cstddef>

// Sizes (fixed by the problem)
#define QLD 1544          // q row stride (16B-aligned), cols [0,1540) valid
#define NQPAD 1664        // padded N dim for q-GEMM (13 * 128)

typedef __bf16 bf16x8 __attribute__((ext_vector_type(8)));
typedef float  f32x4  __attribute__((ext_vector_type(4)));
typedef unsigned short ushort_t;

__device__ __forceinline__ unsigned short f2bf(float f) {
  union { float f; unsigned u; } v; v.f = f;
  unsigned r = v.u + 0x7fffu + ((v.u >> 16) & 1u);
  return (unsigned short)(r >> 16);
}
__device__ __forceinline__ float bf2f(unsigned short h) {
  union { unsigned u; float f; } v; v.u = ((unsigned)h) << 16;
  return v.f;
}
__device__ __forceinline__ float elu_f(float x) { return x > 0.f ? x : expm1f(x); }

// async global -> LDS, 16B per lane; lds base must be wave-uniform (HW: base + lane*16)
__device__ __forceinline__ void cp16_lds(const ushort_t* g, ushort_t* l) {
  __builtin_amdgcn_global_load_lds(
      (const __attribute__((address_space(1))) void*)g,
      (__attribute__((address_space(3))) void*)l, 16, 0, 0);
}

// ---------------- zero helper ----------------
__global__ void k_zero(float* p, int n) {
  int i = blockIdx.x * blockDim.x + threadIdx.x;
  if (i < n) p[i] = 0.f;
}

// ---------------- GIN aggregation ----------------
__global__ void k_agg(const float* __restrict__ x, const float* __restrict__ adjs,
                      const float* __restrict__ flags,
                      float* __restrict__ h0, float* __restrict__ concat) {
  const int bi = blockIdx.x;           // 0..1023  (b*64+i)
  const int b = bi >> 6, i = bi & 63;
  const int f = threadIdx.x;           // 0..127
  __shared__ float sa[64], sm[64];
  if (f < 64) {
    float m = flags[b * 64 + i] * flags[b * 64 + f];
    float a = adjs[(size_t)(b * 64 + i) * 64 + f] * m;
    sa[f] = a; sm[f] = m;
  }
  __syncthreads();
  float s0 = 0.f, s1 = 0.f;
  const float* xb = x + (size_t)b * 64 * 128;
  for (int j = 0; j < 64; ++j) {
    float xv = xb[j * 128 + f];
    s0 = fmaf(sa[j], xv, s0);
    s1 = fmaf(sm[j] - sa[j], xv, s1);
  }
  h0[(size_t)bi * 256 + f]       = s0;
  h0[(size_t)bi * 256 + 128 + f] = s1;
  concat[(size_t)bi * 384 + f]   = xb[i * 128 + f];
}

// ---------------- small fp32 GEMM ----------------
__global__ __launch_bounds__(256) void k_sgemm(
    const float* __restrict__ A, const float* __restrict__ Bm,
    float* __restrict__ Cf, ushort_t* __restrict__ Cb,
    const float* __restrict__ bias, const float* __restrict__ rowscale,
    int K, int lda, int ldb, int ldc, int act) {
  __shared__ float As[64 * 17];
  __shared__ float Bs[16 * 64];
  const int tid = threadIdx.x;
  const int tx = tid & 15, ty = tid >> 4;
  const int m0 = blockIdx.y * 64, n0 = blockIdx.x * 64;
  float acc[4][4] = {};
  for (int k0 = 0; k0 < K; k0 += 16) {
#pragma unroll
    for (int i = 0; i < 4; i++) {
      int e = tid + i * 256;
      int r = e >> 4, c = e & 15;
      As[r * 17 + c] = A[(size_t)(m0 + r) * lda + k0 + c];
      int rb = e >> 6, cb = e & 63;
      Bs[e] = Bm[(size_t)(k0 + rb) * ldb + n0 + cb];
    }
    __syncthreads();
#pragma unroll
    for (int kk = 0; kk < 16; kk++) {
      float av[4], bv[4];
#pragma unroll
      for (int i = 0; i < 4; i++) av[i] = As[(ty * 4 + i) * 17 + kk];
#pragma unroll
      for (int j = 0; j < 4; j++) bv[j] = Bs[kk * 64 + tx * 4 + j];
#pragma unroll
      for (int i = 0; i < 4; i++)
#pragma unroll
        for (int j = 0; j < 4; j++) acc[i][j] = fmaf(av[i], bv[j], acc[i][j]);
    }
    __syncthreads();
  }
#pragma unroll
  for (int i = 0; i < 4; i++) {
    const int mm = m0 + ty * 4 + i;
    const float rs = rowscale ? rowscale[mm] : 1.f;
#pragma unroll
    for (int j = 0; j < 4; j++) {
      const int nn = n0 + tx * 4 + j;
      float v = acc[i][j] + (bias ? bias[nn] : 0.f);
      if (act == 1) v = elu_f(v);
      else if (act == 2) v = tanhf(v);
      v *= rs;
      if (Cf) Cf[(size_t)mm * ldc + nn] = v;
      if (Cb) Cb[(size_t)mm * ldc + nn] = f2bf(v);
    }
  }
}

// ---------------- transpose + cast fp32 -> bf16 ----------------
__global__ void k_castT(const float* __restrict__ in, ushort_t* __restrict__ out,
                        int R, int C, int Cpad, int r0, int ld) {
  __shared__ float t[32][33];
  const int rb = blockIdx.y * 32, cb = blockIdx.x * 32;
  const int tx = threadIdx.x, ty = threadIdx.y;
#pragma unroll
  for (int dy = 0; dy < 32; dy += 8) {
    int r = rb + ty + dy, c = cb + tx;
    t[ty + dy][tx] = (r < R && c < C) ? in[(size_t)(r0 + r) * ld + c] : 0.f;
  }
  __syncthreads();
#pragma unroll
  for (int dy = 0; dy < 32; dy += 8) {
    int c = cb + ty + dy, r = rb + tx;
    if (c < Cpad && r < R) out[(size_t)c * R + r] = f2bf(t[tx][ty + dy]);
  }
}

// ---------------- plain cast fp32 -> bf16 ----------------
__global__ void k_cast(const float* __restrict__ in, ushort_t* __restrict__ out, int n) {
  int i = blockIdx.x * blockDim.x + threadIdx.x;
  if (i < n) out[i] = f2bf(in[i]);
}

// ---------------- bf16 MFMA GEMM (128x128, BK=32, async global_load_lds staging) ----------------
// swz=1: XCD-aware remap (assumes block->XCD = linear%8): each XCD owns whole
// m-panels so the 13 n-blocks of a panel share one L2. Requires gridDim.y%8==0.
__global__ __launch_bounds__(256) void k_gemm(
    const ushort_t* __restrict__ A, const ushort_t* __restrict__ BT,
    float* __restrict__ outF, ushort_t* __restrict__ outB,
    int K, int lda, int ldb, int ldc, int ncap, int swz) {
  __shared__ __align__(16) ushort_t As[128 * 32];
  __shared__ __align__(16) ushort_t Bs[128 * 32];
  const int tid = threadIdx.x;
  const int lane = tid & 63;
  const int wv = tid >> 6;

  int bx = blockIdx.x, by = blockIdx.y;
  if (swz && (gridDim.y & 7) == 0) {
    int nb = gridDim.x;
    int linear = bx + nb * by;
    int xcd = linear & 7;
    int slot = linear >> 3;
    int mper = gridDim.y >> 3;       // m-panels per XCD
    int mp = slot / nb;
    int n  = slot - mp * nb;
    bx = n; by = xcd * mper + mp;
  }
  const int m0 = by * 128;
  const int n0 = bx * 128;
  const int wm = wv >> 1, wn = wv & 1;

  f32x4 z4 = {0.f, 0.f, 0.f, 0.f};
  f32x4 acc[4][4];
#pragma unroll
  for (int i = 0; i < 4; i++)
#pragma unroll
    for (int j = 0; j < 4; j++) acc[i][j] = z4;

  // async staging: per wave, 2 instrs for As + 2 for Bs per k-step.
  // instr covers 16 rows x 64B = 1024B contiguous LDS; lane L -> row L>>2, byte (L&3)*16.
  const int sr = lane >> 2;          // 0..15
  const int sc = (lane & 3) * 8;     // element col
  const ushort_t* gA0 = A + (size_t)(m0 + wv * 32 + sr) * lda + sc;
  const ushort_t* gA1 = gA0 + (size_t)16 * lda;
  const ushort_t* gB0 = BT + (size_t)(n0 + wv * 32 + sr) * ldb + sc;
  const ushort_t* gB1 = gB0 + (size_t)16 * ldb;
  ushort_t* lA0 = &As[(wv * 32) * 32];      // wave-uniform LDS bases
  ushort_t* lA1 = &As[(wv * 32 + 16) * 32];
  ushort_t* lB0 = &Bs[(wv * 32) * 32];
  ushort_t* lB1 = &Bs[(wv * 32 + 16) * 32];

  const int fr = lane & 15;          // m/n within frag
  const int fq = (lane >> 4) * 8;    // k offset

  for (int k0 = 0; k0 < K; k0 += 32) {
    cp16_lds(gA0 + k0, lA0);
    cp16_lds(gA1 + k0, lA1);
    cp16_lds(gB0 + k0, lB0);
    cp16_lds(gB1 + k0, lB1);
    __syncthreads();
    bf16x8 af[4], bfv[4];
#pragma unroll
    for (int f = 0; f < 4; ++f) {
      af[f]  = *reinterpret_cast<const bf16x8*>(&As[(wm * 64 + f * 16 + fr) * 32 + fq]);
      bfv[f] = *reinterpret_cast<const bf16x8*>(&Bs[(wn * 64 + f * 16 + fr) * 32 + fq]);
    }
#pragma unroll
    for (int fm = 0; fm < 4; ++fm)
#pragma unroll
      for (int fn = 0; fn < 4; ++fn)
        acc[fm][fn] = __builtin_amdgcn_mfma_f32_16x16x32_bf16(af[fm], bfv[fn], acc[fm][fn], 0, 0, 0);
    __syncthreads();
  }

  // C/D layout: col = lane&15, row = (lane>>4)*4 + reg  [m89-verified]
  const int er = (lane >> 4) * 4;
  const int ec = lane & 15;
#pragma unroll
  for (int fm = 0; fm < 4; ++fm) {
#pragma unroll
    for (int fn = 0; fn < 4; ++fn) {
      const int nn = n0 + wn * 64 + fn * 16 + ec;
      if (nn >= ncap) continue;
#pragma unroll
      for (int r = 0; r < 4; ++r) {
        const int mm = m0 + wm * 64 + fm * 16 + er + r;
        float v = acc[fm][fn][r];
        if (outF) outF[(size_t)mm * ldc + nn] = v;
        if (outB) outB[(size_t)mm * ldc + nn] = f2bf(v);
      }
    }
  }
}

// ---------------- d[n] = sum_m b2t[m] * W1r[2+m, n] ----------------
__global__ void k_dvec(const float* __restrict__ b2t, const float* __restrict__ W1r,
                       float* __restrict__ dvec) {
  int n = blockIdx.x * 256 + threadIdx.x;
  if (n >= 1540) return;
  float s = 0.f;
  for (int m2 = 0; m2 < 768; ++m2)
    s = fmaf(b2t[m2], W1r[(size_t)(2 + m2) * 1540 + n], s);
  dvec[n] = s;
}

// ---------------- BN stats over virtual h1 (j-split) ----------------
__global__ __launch_bounds__(256) void k_stats(
    const float* __restrict__ UV, const float* __restrict__ adjs,
    const float* __restrict__ flags, const float* __restrict__ W1t,
    const float* __restrict__ b1t, float* __restrict__ colsum, float* __restrict__ colss) {
  const int bi = blockIdx.x, b = bi >> 6;
  const int j0 = blockIdx.y * 16;
  const int t = threadIdx.x;
  const float fi = flags[bi];
  const float* Urow = UV + (size_t)bi * 3072;
  float u[6], w0[6], w1[6], bb[6], sum[6], ss[6];
#pragma unroll
  for (int c = 0; c < 6; c++) {
    int n = t + 256 * c;
    u[c] = Urow[n]; w0[c] = W1t[n]; w1[c] = W1t[1536 + n]; bb[c] = b1t[n];
    sum[c] = 0.f; ss[c] = 0.f;
  }
  for (int j = j0; j < j0 + 16; ++j) {
    float m = fi * flags[b * 64 + j];
    float a0 = adjs[(size_t)bi * 64 + j] * m;
    float a1 = m - a0;
    const float* Vrow = UV + (size_t)(b * 64 + j) * 3072 + 1536;
#pragma unroll
    for (int c = 0; c < 6; c++) {
      float h = u[c] + Vrow[t + 256 * c] + a0 * w0[c] + a1 * w1[c] + bb[c];
      sum[c] += h; ss[c] = fmaf(h, h, ss[c]);
    }
  }
#pragma unroll
  for (int c = 0; c < 6; c++) {
    atomicAdd(&colsum[t + 256 * c], sum[c]);
    atomicAdd(&colss[t + 256 * c], ss[c]);
  }
}

// ---------------- finalize BN scale/shift ----------------
__global__ void k_bnfin(const float* __restrict__ colsum, const float* __restrict__ colss,
                        const float* __restrict__ gamma, const float* __restrict__ beta,
                        float* __restrict__ bns, float* __restrict__ bnt) {
  int n = blockIdx.x * 256 + threadIdx.x;
  if (n >= 1536) return;
  float mu = colsum[n] * (1.f / 65536.f);
  float var = colss[n] * (1.f / 65536.f) - mu * mu;
  float s = gamma[n] * rsqrtf(var + 1e-5f);
  bns[n] = s;
  bnt[n] = beta[n] - mu * s;
}

// ---------------- hmid: edge-parallel, one block per edge row ----------------
__global__ __launch_bounds__(256) void k_act2(
    const float* __restrict__ UV, const float* __restrict__ adjs,
    const float* __restrict__ flags, const float* __restrict__ W1t,
    const float* __restrict__ b1t, const float* __restrict__ bns,
    const float* __restrict__ bnt, ushort_t* __restrict__ hmid, int bi0) {
  const int e = blockIdx.x;
  const int bi = bi0 + (e >> 6);
  const int j = e & 63;
  const int b = bi >> 6;
  const int t = threadIdx.x;
  const float m = flags[bi] * flags[b * 64 + j];
  const float a0 = adjs[(size_t)bi * 64 + j] * m;
  const float a1 = m - a0;
  const float* Urow = UV + (size_t)bi * 3072;
  const float* Vrow = UV + (size_t)(b * 64 + j) * 3072 + 1536;
  ushort_t* hrow = hmid + (size_t)e * 1536;
#pragma unroll
  for (int c = 0; c < 6; c++) {
    int n = t + 256 * c;
    float h = Urow[n] + Vrow[n] + a0 * W1t[n] + a1 * W1t[1536 + n] + b1t[n];
    float v = fmaf(h, bns[n], bnt[n]);
    hrow[n] = f2bf(elu_f(v));
  }
}

// ---------------- score chunk ----------------
__global__ __launch_bounds__(256) void k_score(
    const ushort_t* __restrict__ q, const float* __restrict__ adjs,
    const float* __restrict__ flags, const float* __restrict__ dvec,
    const float* __restrict__ W1r, const float* __restrict__ b1r,
    const float* __restrict__ W2r, const float* __restrict__ b2r,
    float* __restrict__ out, int b0) {
  const int i = blockIdx.x, j = blockIdx.y, bl = blockIdx.z;
  const int b = b0 + bl;
  if (i > j) return;
  const int t = threadIdx.x;
  if (i == j) { if (t == 0) out[((size_t)b * 64 + i) * 64 + j] = 0.f; return; }
  float fi = flags[b * 64 + i], fj = flags[b * 64 + j], m = fi * fj;
  float adij = adjs[((size_t)b * 64 + i) * 64 + j];
  float adji = adjs[((size_t)b * 64 + j) * 64 + i];
  float a0ij = adij * m, a1ij = m - a0ij;
  float a0ji = adji * m, a1ji = m - a0ji;
  const ushort_t* qij = q + (((size_t)bl * 64 + i) * 64 + j) * QLD;
  const ushort_t* qji = q + (((size_t)bl * 64 + j) * 64 + i) * QLD;
  float sij = 0.f, sji = 0.f;
  for (int n = t; n < 1540; n += 256) {
    float quv = bf2f(qij[n]) + bf2f(qji[n]) + 2.f * dvec[n];
    float base = m * quv + b1r[n];
    float w0 = W1r[n], w1 = W1r[1540 + n], w2 = W2r[n];
    float zij = base + a0ij * w0 + a1ij * w1;
    float zji = base + a0ji * w0 + a1ji * w1;
    sij = fmaf(elu_f(zij), w2, sij);
    sji = fmaf(elu_f(zji), w2, sji);
  }
  __shared__ float red[512];
  red[t] = sij; red[256 + t] = sji;
  __syncthreads();
  for (int s2 = 128; s2 > 0; s2 >>= 1) {
    if (t < s2) { red[t] += red[t + s2]; red[256 + t] += red[256 + t + s2]; }
    __syncthreads();
  }
  if (t == 0) {
    out[((size_t)b * 64 + i) * 64 + j] = red[0]   + b2r[0];
    out[((size_t)b * 64 + j) * 64 + i] = red[256] + b2r[0];
  }
}

extern "C" void kernel_launch(void* const* d_in, const int* in_sizes, int n_in,
                              void* d_out, int out_size, void* d_ws, size_t ws_size,
                              hipStream_t stream) {
  const float* x     = (const float*)d_in[0];
  const float* adjs  = (const float*)d_in[1];
  const float* flags = (const float*)d_in[2];
  const float* Wg    = (const float*)d_in[3];
  const float* bg    = (const float*)d_in[4];
  const float* Wout  = (const float*)d_in[5];
  const float* bout  = (const float*)d_in[6];
  const float* W1t   = (const float*)d_in[7];
  const float* b1t   = (const float*)d_in[8];
  const float* gamma = (const float*)d_in[9];
  const float* beta  = (const float*)d_in[10];
  const float* W2t   = (const float*)d_in[11];
  const float* b2t   = (const float*)d_in[12];
  const float* W1r   = (const float*)d_in[13];
  const float* b1r   = (const float*)d_in[14];
  const float* W2r   = (const float*)d_in[15];
  const float* b2r   = (const float*)d_in[16];
  float* out_score = (float*)d_out;
  float* out_xo    = (float*)d_out + 65536;

  uint8_t* ws = (uint8_t*)d_ws;
  size_t off = 0;
  auto alloc = [&](size_t bytes) -> void* {
    void* p = ws + off;
    off += (bytes + 255) & ~(size_t)255;
    return p;
  };
  float*    h0      = (float*)   alloc((size_t)1024 * 256 * 4);
  float*    concat  = (float*)   alloc((size_t)1024 * 384 * 4);
  ushort_t* xo_bf   = (ushort_t*)alloc((size_t)1024 * 768 * 2);
  ushort_t* W1tT    = (ushort_t*)alloc((size_t)3072 * 768 * 2);
  ushort_t* W2t_bf  = (ushort_t*)alloc((size_t)1536 * 768 * 2);
  ushort_t* WrxT    = (ushort_t*)alloc((size_t)NQPAD * 768 * 2);
  ushort_t* WcT     = (ushort_t*)alloc((size_t)NQPAD * 1536 * 2);
  float*    UV      = (float*)   alloc((size_t)1024 * 3072 * 4);
  float*    dvec    = (float*)   alloc((size_t)1664 * 4);
  float*    colsum  = (float*)   alloc((size_t)1536 * 4);
  float*    colss   = (float*)   alloc((size_t)1536 * 4);
  float*    bns     = (float*)   alloc((size_t)1536 * 4);
  float*    bnt     = (float*)   alloc((size_t)1536 * 4);

  // Adaptive chunk size: largest CHB (batches per chunk) that fits ws.
  int cb = 2;
  {
    const int cands[4] = {16, 8, 4, 2};
    for (int ci = 0; ci < 4; ++ci) {
      int c = cands[ci];
      size_t need = off + ((size_t)c * 4096 * 1536 * 2 + 256)
                        + ((size_t)c * 4096 * QLD * 2 + 256);
      if (need <= ws_size) { cb = c; break; }
    }
  }
  ushort_t* hmid_c  = (ushort_t*)alloc((size_t)cb * 4096 * 1536 * 2);
  ushort_t* q_c     = (ushort_t*)alloc((size_t)cb * 4096 * QLD * 2);
  (void)in_sizes; (void)n_in; (void)out_size;

  // BN accumulators must be zeroed every launch (ws is poisoned)
  k_zero<<<dim3(12), dim3(256), 0, stream>>>(colsum, 3072);

  // GIN chain (fp32 — x_o is a direct output)
  k_agg<<<dim3(1024), dim3(128), 0, stream>>>(x, adjs, flags, h0, concat);
  k_sgemm<<<dim3(4, 16), dim3(256), 0, stream>>>(h0, Wg, concat + 128, (ushort_t*)nullptr,
                                                 bg, flags, 256, 256, 256, 384, 1);
  k_sgemm<<<dim3(12, 16), dim3(256), 0, stream>>>(concat, Wout, out_xo, xo_bf,
                                                  bout, flags, 384, 384, 768, 768, 2);

  // weight casts / transposes
  k_castT<<<dim3(48, 24), dim3(32, 8), 0, stream>>>(W1t, W1tT, 768, 1536, 1536, 2, 1536);
  k_castT<<<dim3(48, 24), dim3(32, 8), 0, stream>>>(W1t, W1tT + (size_t)1536 * 768, 768, 1536, 1536, 770, 1536);
  k_castT<<<dim3(52, 24), dim3(32, 8), 0, stream>>>(W1r, WrxT, 768, 1540, NQPAD, 2, 1540);
  k_cast<<<dim3(4608), dim3(256), 0, stream>>>(W2t, W2t_bf, 1536 * 768);

  // UV = x_o @ [W1t_i | W1t_j]   (fp32 out)
  k_gemm<<<dim3(24, 8), dim3(256), 0, stream>>>(xo_bf, W1tT, UV, (ushort_t*)nullptr,
                                                768, 768, 768, 3072, 3072, 0);
  // WcT = (W2t @ W1r[2:770])^T  (bf16 out)
  k_gemm<<<dim3(12, 13), dim3(256), 0, stream>>>(WrxT, W2t_bf, (float*)nullptr, WcT,
                                                 768, 768, 768, 1536, 1536, 0);
  k_dvec<<<dim3(7), dim3(256), 0, stream>>>(b2t, W1r, dvec);

  // BN stats over virtual h1 (full dataset), finalize
  k_stats<<<dim3(1024, 4), dim3(256), 0, stream>>>(UV, adjs, flags, W1t, b1t, colsum, colss);
  k_bnfin<<<dim3(6), dim3(256), 0, stream>>>(colsum, colss, gamma, beta, bns, bnt);

  // chunked heavy pipeline: act -> q-GEMM -> score
  for (int b0 = 0; b0 < 16; b0 += cb) {
    k_act2<<<dim3(cb * 4096), dim3(256), 0, stream>>>(UV, adjs, flags, W1t, b1t, bns, bnt,
                                                      hmid_c, b0 * 64);
    k_gemm<<<dim3(13, cb * 32), dim3(256), 0, stream>>>(hmid_c, WcT, (float*)nullptr, q_c,
                                                        1536, 1536, 1536, QLD, 1540, 1);
    k_score<<<dim3(64, 64, cb), dim3(256), 0, stream>>>(q_c, adjs, flags, dvec,
                                                        W1r, b1r, W2r, b2r, out_score, b0);
  }
}